// Round 1
// baseline (2176.055 us; speedup 1.0000x reference)
//
#include <hip/hip_runtime.h>
#include <stdint.h>

// Echo-state network (fp32 in, fp32 out). Round 15: kill the A-operand LDS
// round-trip. R14 analysis: per-chunk LDS traffic 216 KB/CU (A write 48 +
// A read 48 + B write 24 + B read 96) >> MFMA 700 cy -> LDS-BW-bound.
// A fragments are wave-private (wm-indexed rows, zero cross-wave reuse) and
// their MFMA layout (row = l16, 8 contiguous K elems at kk+oct*8) equals the
// row-major global layout of the state, so A is now loaded DIRECTLY
// global->VGPR (prefetched one chunk ahead). B (4x cross-wave reuse) stays in
// LDS but is double-buffered -> ONE __syncthreads per chunk (was 2).
// W_in/X handled as a 17th chunk via the same dbuf slots. Everything else
// (hi/lo*4096 f16 split, 3 MFMAs/product, 768-block grid, fused head partials
// + head_reduce) identical to R14.

typedef _Float16 f16;
typedef _Float16 f16x8 __attribute__((ext_vector_type(8)));
typedef float floatx4 __attribute__((ext_vector_type(4)));

#define N_TOT 256
#define T_TOT 70
#define V_TOT 64
#define B_TOT 6
#define H_TOT 1024
#define C_TOT 4
#define F_TOT (B_TOT * H_TOT)
#define G_TOT 192       // partial groups = B_TOT * 32 unit-tiles
#define LDB 72          // f16 LDS row stride (144 B): <=2-way bank aliasing (free)
#define LO_SCALE 4096.0f
#define LO_INV   (1.0f / 4096.0f)

union H8 { f16 h[8]; uint4 v; f16x8 f; };

// ---------------------------------------------------------------------------
// One-time fp32 -> (hi, lo*4096) f16 split, 8 elems/thread. n % 2048 == 0.
// ---------------------------------------------------------------------------
__global__ __launch_bounds__(256)
void split_f32(const float* __restrict__ src, f16* __restrict__ hi,
               f16* __restrict__ lo, int n)
{
    const int i = (blockIdx.x * 256 + threadIdx.x) * 8;
    if (i + 8 > n) return;
    const float4 a = *(const float4*)&src[i];
    const float4 b = *(const float4*)&src[i + 4];
    const float x[8] = {a.x, a.y, a.z, a.w, b.x, b.y, b.z, b.w};
    H8 H, L;
#pragma unroll
    for (int j = 0; j < 8; ++j) {
        const f16 h = (f16)x[j];
        H.h[j] = h;
        L.h[j] = (f16)((x[j] - (float)h) * LO_SCALE);
    }
    *(uint4*)&hi[i] = H.v;
    *(uint4*)&lo[i] = L.v;
}

// ---------------------------------------------------------------------------
// Final head reduce + argmax. Block = t (70), thread = n (256).
// logits[t][n][c] = b_lin[t][c] + sum_g part[t][g][n][c]; preds = argmax.
// ---------------------------------------------------------------------------
__global__ __launch_bounds__(256)
void head_reduce(const float* __restrict__ part,
                 const float* __restrict__ b_lin,
                 float* __restrict__ logits,
                 float* __restrict__ preds)
{
    const int t = blockIdx.x;
    const int n = threadIdx.x;

    float a0 = b_lin[t * C_TOT + 0];
    float a1 = b_lin[t * C_TOT + 1];
    float a2 = b_lin[t * C_TOT + 2];
    float a3 = b_lin[t * C_TOT + 3];

    const float* p = part + (((size_t)t * G_TOT) * N_TOT + n) * C_TOT;
    for (int g = 0; g < G_TOT; ++g) {
        const float4 v = *(const float4*)&p[(size_t)g * N_TOT * C_TOT];
        a0 += v.x; a1 += v.y; a2 += v.z; a3 += v.w;
    }

    float4 o = {a0, a1, a2, a3};
    *(float4*)&logits[((size_t)t * N_TOT + n) * C_TOT] = o;

    int arg = 0;
    float best = a0;
    if (a1 > best) { best = a1; arg = 1; }
    if (a2 > best) { best = a2; arg = 2; }
    if (a3 > best) { best = a3; arg = 3; }
    preds[(size_t)t * N_TOT + n] = (float)arg;
}

// ---------------------------------------------------------------------------
// Fused step+head: S_new = tanh(S W_res^T + X_t W_in^T); partials -> part[].
// Tile 64(M=batch) x 32(I=units); grid = 6*4*32 = 768, 4 waves (M-quadrants),
// each wave 1x2 16x16x32 f16 fragments. BK=64.
// A: direct global->reg fragments, 1-chunk prefetch. B: LDS double-buffer,
// one barrier per chunk.
// ---------------------------------------------------------------------------
__global__ __launch_bounds__(256, 3)
void esn_step_fused(const f16* __restrict__ Xhi,   const f16* __restrict__ Xlo,
                    const f16* __restrict__ Whi,   const f16* __restrict__ Wlo,
                    const f16* __restrict__ Wihi,  const f16* __restrict__ Wilo,
                    const f16* __restrict__ shi_p, const f16* __restrict__ slo_p,
                    f16* __restrict__ shi_n,       f16* __restrict__ slo_n,
                    const float* __restrict__ W_lin, float* __restrict__ part,
                    int t, int first)
{
    __shared__ f16 Bs_hi[2][32 * LDB];
    __shared__ f16 Bs_lo[2][32 * LDB];

    const int id  = blockIdx.x;
    const int b   = id >> 7;         // reservoir block 0..5
    const int rem = id & 127;
    const int mt  = rem >> 5;        // batch tile 0..3  (64 rows)
    const int it  = rem & 31;        // unit tile 0..31  (32 cols)

    const int tid  = threadIdx.x;
    const int wm   = tid >> 6;       // wave = M-quadrant
    const int lane = tid & 63;
    const int l16  = lane & 15;
    const int oct  = lane >> 4;

    // B staging map (f16 elements, uint4 = 8 f16)
    const int rb = tid >> 3;          // B row 0..31
    const int cb = (tid & 7) << 3;    // B col {0,8,...,56}: 1 uint4 per buffer

    floatx4 acc[2], accl[2];
#pragma unroll
    for (int j = 0; j < 2; ++j) { acc[j] = (floatx4)(0.0f); accl[j] = (floatx4)(0.0f); }

    // per-lane A row for this wave's fragments (MFMA A layout == row-major)
    const int arow = mt * 64 + wm * 16 + l16;          // batch row 0..255

    const f16* Xh = Xhi + ((size_t)arow * T_TOT + t) * V_TOT;
    const f16* Xl = Xlo + ((size_t)arow * T_TOT + t) * V_TOT;
    const f16* Bwh = Wihi + (size_t)(b * H_TOT + it * 32 + rb) * V_TOT + cb;
    const f16* Bwl = Wilo + (size_t)(b * H_TOT + it * 32 + rb) * V_TOT + cb;

    H8 ah0, ah1, al0, al1;            // current-chunk A fragments (kk=0, kk=32)

    if (!first) {
        const f16* Ah = shi_p + (size_t)(b * N_TOT + arow) * H_TOT;
        const f16* Al = slo_p + (size_t)(b * N_TOT + arow) * H_TOT;
        const f16* Bh = Whi   + (size_t)(b * H_TOT + it * 32 + rb) * H_TOT + cb;
        const f16* Bl = Wlo   + (size_t)(b * H_TOT + it * 32 + rb) * H_TOT + cb;

        // prologue: B(0) -> LDS[0]; B(1) -> regs; A(0) -> regs
        uint4 pbh = *(const uint4*)&Bh[0];
        uint4 pbl = *(const uint4*)&Bl[0];
        *(uint4*)&Bs_hi[0][rb * LDB + cb] = pbh;
        *(uint4*)&Bs_lo[0][rb * LDB + cb] = pbl;
        pbh = *(const uint4*)&Bh[64];
        pbl = *(const uint4*)&Bl[64];
        ah0.v = *(const uint4*)&Ah[oct * 8];
        ah1.v = *(const uint4*)&Ah[32 + oct * 8];
        al0.v = *(const uint4*)&Al[oct * 8];
        al1.v = *(const uint4*)&Al[32 + oct * 8];
        __syncthreads();

        for (int kc = 0; kc < 16; ++kc) {
            const int cur = kc & 1;

            // store next B tile: B(kc+1), or W_in tile at kc==15.
            // Safe: barrier at end of kc-1 covered all reads of buf cur^1.
            *(uint4*)&Bs_hi[cur ^ 1][rb * LDB + cb] = pbh;
            *(uint4*)&Bs_lo[cur ^ 1][rb * LDB + cb] = pbl;
            if (kc < 14) {
                pbh = *(const uint4*)&Bh[(kc + 2) * 64];
                pbl = *(const uint4*)&Bl[(kc + 2) * 64];
            } else if (kc == 14) {      // B(16) = input-term W_in tile
                pbh = *(const uint4*)&Bwh[0];
                pbl = *(const uint4*)&Bwl[0];
            }

            // prefetch next A fragments (A(kc+1), or X_t frags at kc==15)
            H8 nh0, nh1, nl0, nl1;
            if (kc < 15) {
                const int ko = (kc + 1) * 64 + oct * 8;
                nh0.v = *(const uint4*)&Ah[ko];
                nh1.v = *(const uint4*)&Ah[ko + 32];
                nl0.v = *(const uint4*)&Al[ko];
                nl1.v = *(const uint4*)&Al[ko + 32];
            } else {
                nh0.v = *(const uint4*)&Xh[oct * 8];
                nh1.v = *(const uint4*)&Xh[32 + oct * 8];
                nl0.v = *(const uint4*)&Xl[oct * 8];
                nl1.v = *(const uint4*)&Xl[32 + oct * 8];
            }

            // compute on Bs[cur] with in-reg A fragments
#pragma unroll
            for (int half = 0; half < 2; ++half) {
                const int kk = half * 32;
                const f16x8 ah = half ? ah1.f : ah0.f;
                const f16x8 al = half ? al1.f : al0.f;
#pragma unroll
                for (int nf = 0; nf < 2; ++nf) {
                    const int br = (nf * 16 + l16) * LDB + kk + oct * 8;
                    const f16x8 bh = *(const f16x8*)&Bs_hi[cur][br];
                    const f16x8 bl = *(const f16x8*)&Bs_lo[cur][br];
                    acc[nf]  = __builtin_amdgcn_mfma_f32_16x16x32_f16(ah, bh, acc[nf], 0, 0, 0);
                    accl[nf] = __builtin_amdgcn_mfma_f32_16x16x32_f16(ah, bl, accl[nf], 0, 0, 0);
                    accl[nf] = __builtin_amdgcn_mfma_f32_16x16x32_f16(al, bh, accl[nf], 0, 0, 0);
                }
            }
            __syncthreads();   // buf cur reads done; buf cur^1 stores visible
            ah0 = nh0; ah1 = nh1; al0 = nl0; al1 = nl1;
        }
        // post-loop: Bs[0] holds W_in tile (stored at kc==15), A regs hold X.
    } else {
        // t == 0: state is zero; only the input term.
        uint4 pbh = *(const uint4*)&Bwh[0];
        uint4 pbl = *(const uint4*)&Bwl[0];
        *(uint4*)&Bs_hi[0][rb * LDB + cb] = pbh;
        *(uint4*)&Bs_lo[0][rb * LDB + cb] = pbl;
        ah0.v = *(const uint4*)&Xh[oct * 8];
        ah1.v = *(const uint4*)&Xh[32 + oct * 8];
        al0.v = *(const uint4*)&Xl[oct * 8];
        al1.v = *(const uint4*)&Xl[32 + oct * 8];
        __syncthreads();
    }

    // ---- input term: += X_t * W_in[b]^T  (K = V = 64), B tile in Bs[0] ----
#pragma unroll
    for (int half = 0; half < 2; ++half) {
        const int kk = half * 32;
        const f16x8 ah = half ? ah1.f : ah0.f;
        const f16x8 al = half ? al1.f : al0.f;
#pragma unroll
        for (int nf = 0; nf < 2; ++nf) {
            const int br = (nf * 16 + l16) * LDB + kk + oct * 8;
            const f16x8 bh = *(const f16x8*)&Bs_hi[0][br];
            const f16x8 bl = *(const f16x8*)&Bs_lo[0][br];
            acc[nf]  = __builtin_amdgcn_mfma_f32_16x16x32_f16(ah, bh, acc[nf], 0, 0, 0);
            accl[nf] = __builtin_amdgcn_mfma_f32_16x16x32_f16(ah, bl, accl[nf], 0, 0, 0);
            accl[nf] = __builtin_amdgcn_mfma_f32_16x16x32_f16(al, bh, accl[nf], 0, 0, 0);
        }
    }

    // ---- epilogue: tanh -> split-store state; head partial -> part[] ----
    // C/D map (16x16x32): col = lane&15, row = oct*4 + r.
    const int nbase = mt * 64;
    const int ibase = it * 32;

    const float* wl = W_lin + (size_t)t * C_TOT * F_TOT + b * H_TOT + ibase;
    float w[4][2];
#pragma unroll
    for (int c = 0; c < 4; ++c)
#pragma unroll
        for (int nf = 0; nf < 2; ++nf)
            w[c][nf] = wl[(size_t)c * F_TOT + nf * 16 + l16];

    float sval[2][4];
#pragma unroll
    for (int nf = 0; nf < 2; ++nf)
#pragma unroll
        for (int r = 0; r < 4; ++r) {
            const int m  = wm * 16 + oct * 4 + r;   // batch row within tile
            const int ii = nf * 16 + l16;           // unit col within tile
            const float s = tanhf(acc[nf][r] + accl[nf][r] * LO_INV);
            sval[nf][r] = s;
            const f16 h = (f16)s;
            const size_t oidx = (size_t)(b * N_TOT + nbase + m) * H_TOT + ibase + ii;
            shi_n[oidx] = h;
            slo_n[oidx] = (f16)((s - (float)h) * LO_SCALE);
        }

    const int g = b * 32 + it;
#pragma unroll
    for (int r = 0; r < 4; ++r) {
        float v[4];
#pragma unroll
        for (int c = 0; c < 4; ++c) {
            float x = sval[0][r] * w[c][0] + sval[1][r] * w[c][1];
            x += __shfl_xor(x, 1);
            x += __shfl_xor(x, 2);
            x += __shfl_xor(x, 4);
            x += __shfl_xor(x, 8);
            v[c] = x;
        }
        if (l16 == 0) {
            const int n = nbase + wm * 16 + oct * 4 + r;
            float4 o = {v[0], v[1], v[2], v[3]};
            *(float4*)&part[(((size_t)t * G_TOT + g) * N_TOT + n) * C_TOT] = o;
        }
    }
}

extern "C" void kernel_launch(void* const* d_in, const int* in_sizes, int n_in,
                              void* d_out, int out_size, void* d_ws, size_t ws_size,
                              hipStream_t stream) {
    const float* X     = (const float*)d_in[0]; // [256,70,64]
    const float* W_res = (const float*)d_in[1]; // [6,1024,1024]
    const float* W_in  = (const float*)d_in[2]; // [6,1024,64]
    const float* W_lin = (const float*)d_in[3]; // [70,4,6144]
    const float* b_lin = (const float*)d_in[4]; // [70,4]

    float* out    = (float*)d_out;
    float* logits = out;                                  // T*N*C fp32
    float* preds  = out + (size_t)T_TOT * N_TOT * C_TOT;  // T*N   fp32

    const size_t nWres = (size_t)B_TOT * H_TOT * H_TOT;   // 6,291,456
    const size_t nWin  = (size_t)B_TOT * H_TOT * V_TOT;   //   393,216
    const size_t nX    = (size_t)N_TOT * T_TOT * V_TOT;   // 1,146,880
    const size_t nS    = (size_t)B_TOT * N_TOT * H_TOT;   // 1,572,864
    const size_t nPart = (size_t)T_TOT * G_TOT * N_TOT * C_TOT;  // 13,762,560
    (void)nPart;

    f16* p    = (f16*)d_ws;                               // f16 arena ~43.9 MB
    f16* Whi  = p;  p += nWres;
    f16* Wlo  = p;  p += nWres;
    f16* Wihi = p;  p += nWin;
    f16* Wilo = p;  p += nWin;
    f16* Xhi  = p;  p += nX;
    f16* Xlo  = p;  p += nX;
    f16* sAh  = p;  p += nS;
    f16* sAl  = p;  p += nS;
    f16* sBh  = p;  p += nS;
    f16* sBl  = p;  p += nS;
    float* part = (float*)p;                              // +55 MB (ws ~268 MB)

    // one-time pre-splits (stream-ordered before the loop)
    split_f32<<<(int)(nWres / 2048), 256, 0, stream>>>(W_res, Whi, Wlo, (int)nWres);
    split_f32<<<(int)(nWin  / 2048), 256, 0, stream>>>(W_in, Wihi, Wilo, (int)nWin);
    split_f32<<<(int)(nX    / 2048), 256, 0, stream>>>(X, Xhi, Xlo, (int)nX);

    for (int t = 0; t < T_TOT; ++t) {
        const f16 *ph, *pl;
        f16 *nh, *nl;
        if (t & 1) { ph = sBh; pl = sBl; nh = sAh; nl = sAl; }
        else       { ph = sAh; pl = sAl; nh = sBh; nl = sBl; }
        esn_step_fused<<<B_TOT * 4 * 32, 256, 0, stream>>>(
            Xhi, Xlo, Whi, Wlo, Wihi, Wilo, ph, pl, nh, nl,
            W_lin, part, t, t == 0 ? 1 : 0);
    }
    head_reduce<<<T_TOT, 256, 0, stream>>>(part, b_lin, logits, preds);
}

// Round 2
// 2166.668 us; speedup vs baseline: 1.0043x; 1.0043x over previous
//
#include <hip/hip_runtime.h>
#include <stdint.h>

// Echo-state network (fp32 in, fp32 out). Round 16: counted-vmcnt barriers.
// R15 post-mortem: the step kernel is barrier/latency-bound, not LDS-BW-bound.
// __syncthreads() compiles to s_waitcnt vmcnt(0) lgkmcnt(0); s_barrier -> every
// per-chunk barrier DRAINED all in-flight global prefetch loads, serializing
// ~400-900 cy of L2/L3 latency with each chunk's compute. Fix (T4): replace
// __syncthreads with {sched_barrier(0); s_waitcnt lgkmcnt(0); s_barrier;
// sched_barrier(0)}. The barrier now only publishes LDS writes; global loads
// stay in flight across it and are retired by compiler-inserted COUNTED
// vmcnt(N) waits at their actual consumers (ds_write of B regs, MFMA of A
// frags). Also: H8 unions removed from the hot kernel (uint4 + bit_cast only;
// no SROA/scratch risk). Dataflow identical to R15: A operand (state / X_t)
// direct global->VGPR fragments prefetched 1 chunk ahead (MFMA A layout ==
// row-major global layout, zero cross-wave reuse so LDS staging was waste);
// B (W_res / W_in, 4x cross-wave reuse) LDS double-buffered, 1 barrier/chunk.
// hi/lo*4096 f16 split, 3 MFMAs/product, 768-block grid, fused head partials
// + head_reduce unchanged.

typedef _Float16 f16;
typedef _Float16 f16x8 __attribute__((ext_vector_type(8)));
typedef float floatx4 __attribute__((ext_vector_type(4)));

#define N_TOT 256
#define T_TOT 70
#define V_TOT 64
#define B_TOT 6
#define H_TOT 1024
#define C_TOT 4
#define F_TOT (B_TOT * H_TOT)
#define G_TOT 192       // partial groups = B_TOT * 32 unit-tiles
#define LDB 72          // f16 LDS row stride (144 B): <=2-way bank aliasing (free)
#define LO_SCALE 4096.0f
#define LO_INV   (1.0f / 4096.0f)

union H8 { f16 h[8]; uint4 v; };

static __device__ __forceinline__ f16x8 as_f16x8(uint4 v) {
    return __builtin_bit_cast(f16x8, v);
}

// LDS-publish barrier: waits local ops only; global loads stay in flight.
#define LDS_BARRIER()                                    \
    do {                                                 \
        __builtin_amdgcn_sched_barrier(0);               \
        asm volatile("s_waitcnt lgkmcnt(0)" ::: "memory"); \
        __builtin_amdgcn_s_barrier();                    \
        __builtin_amdgcn_sched_barrier(0);               \
    } while (0)

// ---------------------------------------------------------------------------
// One-time fp32 -> (hi, lo*4096) f16 split, 8 elems/thread. n % 2048 == 0.
// ---------------------------------------------------------------------------
__global__ __launch_bounds__(256)
void split_f32(const float* __restrict__ src, f16* __restrict__ hi,
               f16* __restrict__ lo, int n)
{
    const int i = (blockIdx.x * 256 + threadIdx.x) * 8;
    if (i + 8 > n) return;
    const float4 a = *(const float4*)&src[i];
    const float4 b = *(const float4*)&src[i + 4];
    const float x[8] = {a.x, a.y, a.z, a.w, b.x, b.y, b.z, b.w};
    H8 H, L;
#pragma unroll
    for (int j = 0; j < 8; ++j) {
        const f16 h = (f16)x[j];
        H.h[j] = h;
        L.h[j] = (f16)((x[j] - (float)h) * LO_SCALE);
    }
    *(uint4*)&hi[i] = H.v;
    *(uint4*)&lo[i] = L.v;
}

// ---------------------------------------------------------------------------
// Final head reduce + argmax. Block = t (70), thread = n (256).
// logits[t][n][c] = b_lin[t][c] + sum_g part[t][g][n][c]; preds = argmax.
// ---------------------------------------------------------------------------
__global__ __launch_bounds__(256)
void head_reduce(const float* __restrict__ part,
                 const float* __restrict__ b_lin,
                 float* __restrict__ logits,
                 float* __restrict__ preds)
{
    const int t = blockIdx.x;
    const int n = threadIdx.x;

    float a0 = b_lin[t * C_TOT + 0];
    float a1 = b_lin[t * C_TOT + 1];
    float a2 = b_lin[t * C_TOT + 2];
    float a3 = b_lin[t * C_TOT + 3];

    const float* p = part + (((size_t)t * G_TOT) * N_TOT + n) * C_TOT;
    for (int g = 0; g < G_TOT; ++g) {
        const float4 v = *(const float4*)&p[(size_t)g * N_TOT * C_TOT];
        a0 += v.x; a1 += v.y; a2 += v.z; a3 += v.w;
    }

    float4 o = {a0, a1, a2, a3};
    *(float4*)&logits[((size_t)t * N_TOT + n) * C_TOT] = o;

    int arg = 0;
    float best = a0;
    if (a1 > best) { best = a1; arg = 1; }
    if (a2 > best) { best = a2; arg = 2; }
    if (a3 > best) { best = a3; arg = 3; }
    preds[(size_t)t * N_TOT + n] = (float)arg;
}

// ---------------------------------------------------------------------------
// Fused step+head: S_new = tanh(S W_res^T + X_t W_in^T); partials -> part[].
// Tile 64(M=batch) x 32(I=units); grid = 6*4*32 = 768, 4 waves (M-quadrants),
// each wave 1x2 16x16x32 f16 fragments. BK=64.
// A: direct global->reg fragments, 1-chunk prefetch. B: LDS double-buffer,
// one LDS-only barrier per chunk (global loads ride across barriers).
// ---------------------------------------------------------------------------
__global__ __launch_bounds__(256, 3)
void esn_step_fused(const f16* __restrict__ Xhi,   const f16* __restrict__ Xlo,
                    const f16* __restrict__ Whi,   const f16* __restrict__ Wlo,
                    const f16* __restrict__ Wihi,  const f16* __restrict__ Wilo,
                    const f16* __restrict__ shi_p, const f16* __restrict__ slo_p,
                    f16* __restrict__ shi_n,       f16* __restrict__ slo_n,
                    const float* __restrict__ W_lin, float* __restrict__ part,
                    int t, int first)
{
    __shared__ f16 Bs_hi[2][32 * LDB];
    __shared__ f16 Bs_lo[2][32 * LDB];

    const int id  = blockIdx.x;
    const int b   = id >> 7;         // reservoir block 0..5
    const int rem = id & 127;
    const int mt  = rem >> 5;        // batch tile 0..3  (64 rows)
    const int it  = rem & 31;        // unit tile 0..31  (32 cols)

    const int tid  = threadIdx.x;
    const int wm   = tid >> 6;       // wave = M-quadrant
    const int lane = tid & 63;
    const int l16  = lane & 15;
    const int oct  = lane >> 4;

    // B staging map (f16 elements, uint4 = 8 f16)
    const int rb = tid >> 3;          // B row 0..31
    const int cb = (tid & 7) << 3;    // B col {0,8,...,56}: 1 uint4 per buffer

    floatx4 acc[2], accl[2];
#pragma unroll
    for (int j = 0; j < 2; ++j) { acc[j] = (floatx4)(0.0f); accl[j] = (floatx4)(0.0f); }

    // per-lane A row for this wave's fragments (MFMA A layout == row-major)
    const int arow = mt * 64 + wm * 16 + l16;          // batch row 0..255

    const f16* Xh  = Xhi  + ((size_t)arow * T_TOT + t) * V_TOT;
    const f16* Xl  = Xlo  + ((size_t)arow * T_TOT + t) * V_TOT;
    const f16* Bwh = Wihi + (size_t)(b * H_TOT + it * 32 + rb) * V_TOT + cb;
    const f16* Bwl = Wilo + (size_t)(b * H_TOT + it * 32 + rb) * V_TOT + cb;

    uint4 a0h, a1h, a0l, a1l;        // current-chunk A fragments (kk=0, kk=32)

    if (!first) {
        const f16* Ah = shi_p + (size_t)(b * N_TOT + arow) * H_TOT;
        const f16* Al = slo_p + (size_t)(b * N_TOT + arow) * H_TOT;
        const f16* Bh = Whi   + (size_t)(b * H_TOT + it * 32 + rb) * H_TOT + cb;
        const f16* Bl = Wlo   + (size_t)(b * H_TOT + it * 32 + rb) * H_TOT + cb;

        // prologue: B(0) -> LDS[0]; B(1) -> regs; A(0) -> regs
        {
            const uint4 b0h = *(const uint4*)&Bh[0];
            const uint4 b0l = *(const uint4*)&Bl[0];
            *(uint4*)&Bs_hi[0][rb * LDB + cb] = b0h;
            *(uint4*)&Bs_lo[0][rb * LDB + cb] = b0l;
        }
        uint4 pbh = *(const uint4*)&Bh[64];
        uint4 pbl = *(const uint4*)&Bl[64];
        a0h = *(const uint4*)&Ah[oct * 8];
        a1h = *(const uint4*)&Ah[32 + oct * 8];
        a0l = *(const uint4*)&Al[oct * 8];
        a1l = *(const uint4*)&Al[32 + oct * 8];
        LDS_BARRIER();

        for (int kc = 0; kc < 16; ++kc) {
            const int cur = kc & 1;

            // store next B tile: B(kc+1), or W_in tile at kc==15.
            // Safe: barrier at end of kc-1 covered all reads of buf cur^1.
            // (compiler inserts counted vmcnt wait for pbh/pbl here)
            *(uint4*)&Bs_hi[cur ^ 1][rb * LDB + cb] = pbh;
            *(uint4*)&Bs_lo[cur ^ 1][rb * LDB + cb] = pbl;
            if (kc < 14) {
                pbh = *(const uint4*)&Bh[(kc + 2) * 64];
                pbl = *(const uint4*)&Bl[(kc + 2) * 64];
            } else if (kc == 14) {      // B(16) = input-term W_in tile
                pbh = *(const uint4*)&Bwh[0];
                pbl = *(const uint4*)&Bwl[0];
            }

            // prefetch next A fragments (A(kc+1), or X_t frags at kc==15)
            uint4 n0h, n1h, n0l, n1l;
            if (kc < 15) {
                const int ko = (kc + 1) * 64 + oct * 8;
                n0h = *(const uint4*)&Ah[ko];
                n1h = *(const uint4*)&Ah[ko + 32];
                n0l = *(const uint4*)&Al[ko];
                n1l = *(const uint4*)&Al[ko + 32];
            } else {
                n0h = *(const uint4*)&Xh[oct * 8];
                n1h = *(const uint4*)&Xh[32 + oct * 8];
                n0l = *(const uint4*)&Xl[oct * 8];
                n1l = *(const uint4*)&Xl[32 + oct * 8];
            }

            // compute on Bs[cur] with in-reg A fragments
            // (compiler inserts counted vmcnt wait for a*h/a*l here)
#pragma unroll
            for (int half = 0; half < 2; ++half) {
                const int kk = half * 32;
                const f16x8 ah = as_f16x8(half ? a1h : a0h);
                const f16x8 al = as_f16x8(half ? a1l : a0l);
#pragma unroll
                for (int nf = 0; nf < 2; ++nf) {
                    const int br = (nf * 16 + l16) * LDB + kk + oct * 8;
                    const f16x8 bh = *(const f16x8*)&Bs_hi[cur][br];
                    const f16x8 bl = *(const f16x8*)&Bs_lo[cur][br];
                    acc[nf]  = __builtin_amdgcn_mfma_f32_16x16x32_f16(ah, bh, acc[nf], 0, 0, 0);
                    accl[nf] = __builtin_amdgcn_mfma_f32_16x16x32_f16(ah, bl, accl[nf], 0, 0, 0);
                    accl[nf] = __builtin_amdgcn_mfma_f32_16x16x32_f16(al, bh, accl[nf], 0, 0, 0);
                }
            }
            a0h = n0h; a1h = n1h; a0l = n0l; a1l = n1l;
            LDS_BARRIER();   // publish buf cur^1 writes; reads of cur done
        }
        // post-loop: Bs[0] holds W_in tile (stored at kc==15), A regs hold X.
    } else {
        // t == 0: state is zero; only the input term.
        const uint4 pbh = *(const uint4*)&Bwh[0];
        const uint4 pbl = *(const uint4*)&Bwl[0];
        *(uint4*)&Bs_hi[0][rb * LDB + cb] = pbh;
        *(uint4*)&Bs_lo[0][rb * LDB + cb] = pbl;
        a0h = *(const uint4*)&Xh[oct * 8];
        a1h = *(const uint4*)&Xh[32 + oct * 8];
        a0l = *(const uint4*)&Xl[oct * 8];
        a1l = *(const uint4*)&Xl[32 + oct * 8];
        LDS_BARRIER();
    }

    // ---- input term: += X_t * W_in[b]^T  (K = V = 64), B tile in Bs[0] ----
#pragma unroll
    for (int half = 0; half < 2; ++half) {
        const int kk = half * 32;
        const f16x8 ah = as_f16x8(half ? a1h : a0h);
        const f16x8 al = as_f16x8(half ? a1l : a0l);
#pragma unroll
        for (int nf = 0; nf < 2; ++nf) {
            const int br = (nf * 16 + l16) * LDB + kk + oct * 8;
            const f16x8 bh = *(const f16x8*)&Bs_hi[0][br];
            const f16x8 bl = *(const f16x8*)&Bs_lo[0][br];
            acc[nf]  = __builtin_amdgcn_mfma_f32_16x16x32_f16(ah, bh, acc[nf], 0, 0, 0);
            accl[nf] = __builtin_amdgcn_mfma_f32_16x16x32_f16(ah, bl, accl[nf], 0, 0, 0);
            accl[nf] = __builtin_amdgcn_mfma_f32_16x16x32_f16(al, bh, accl[nf], 0, 0, 0);
        }
    }

    // ---- epilogue: tanh -> split-store state; head partial -> part[] ----
    // C/D map (16x16x32): col = lane&15, row = oct*4 + r.
    const int nbase = mt * 64;
    const int ibase = it * 32;

    const float* wl = W_lin + (size_t)t * C_TOT * F_TOT + b * H_TOT + ibase;
    float w[4][2];
#pragma unroll
    for (int c = 0; c < 4; ++c)
#pragma unroll
        for (int nf = 0; nf < 2; ++nf)
            w[c][nf] = wl[(size_t)c * F_TOT + nf * 16 + l16];

    float sval[2][4];
#pragma unroll
    for (int nf = 0; nf < 2; ++nf)
#pragma unroll
        for (int r = 0; r < 4; ++r) {
            const int m  = wm * 16 + oct * 4 + r;   // batch row within tile
            const int ii = nf * 16 + l16;           // unit col within tile
            const float s = tanhf(acc[nf][r] + accl[nf][r] * LO_INV);
            sval[nf][r] = s;
            const f16 h = (f16)s;
            const size_t oidx = (size_t)(b * N_TOT + nbase + m) * H_TOT + ibase + ii;
            shi_n[oidx] = h;
            slo_n[oidx] = (f16)((s - (float)h) * LO_SCALE);
        }

    const int g = b * 32 + it;
#pragma unroll
    for (int r = 0; r < 4; ++r) {
        float v[4];
#pragma unroll
        for (int c = 0; c < 4; ++c) {
            float x = sval[0][r] * w[c][0] + sval[1][r] * w[c][1];
            x += __shfl_xor(x, 1);
            x += __shfl_xor(x, 2);
            x += __shfl_xor(x, 4);
            x += __shfl_xor(x, 8);
            v[c] = x;
        }
        if (l16 == 0) {
            const int n = nbase + wm * 16 + oct * 4 + r;
            float4 o = {v[0], v[1], v[2], v[3]};
            *(float4*)&part[(((size_t)t * G_TOT + g) * N_TOT + n) * C_TOT] = o;
        }
    }
}

extern "C" void kernel_launch(void* const* d_in, const int* in_sizes, int n_in,
                              void* d_out, int out_size, void* d_ws, size_t ws_size,
                              hipStream_t stream) {
    const float* X     = (const float*)d_in[0]; // [256,70,64]
    const float* W_res = (const float*)d_in[1]; // [6,1024,1024]
    const float* W_in  = (const float*)d_in[2]; // [6,1024,64]
    const float* W_lin = (const float*)d_in[3]; // [70,4,6144]
    const float* b_lin = (const float*)d_in[4]; // [70,4]

    float* out    = (float*)d_out;
    float* logits = out;                                  // T*N*C fp32
    float* preds  = out + (size_t)T_TOT * N_TOT * C_TOT;  // T*N   fp32

    const size_t nWres = (size_t)B_TOT * H_TOT * H_TOT;   // 6,291,456
    const size_t nWin  = (size_t)B_TOT * H_TOT * V_TOT;   //   393,216
    const size_t nX    = (size_t)N_TOT * T_TOT * V_TOT;   // 1,146,880
    const size_t nS    = (size_t)B_TOT * N_TOT * H_TOT;   // 1,572,864

    f16* p    = (f16*)d_ws;                               // f16 arena ~43.9 MB
    f16* Whi  = p;  p += nWres;
    f16* Wlo  = p;  p += nWres;
    f16* Wihi = p;  p += nWin;
    f16* Wilo = p;  p += nWin;
    f16* Xhi  = p;  p += nX;
    f16* Xlo  = p;  p += nX;
    f16* sAh  = p;  p += nS;
    f16* sAl  = p;  p += nS;
    f16* sBh  = p;  p += nS;
    f16* sBl  = p;  p += nS;
    float* part = (float*)p;                              // +55 MB (ws ~268 MB)

    // one-time pre-splits (stream-ordered before the loop)
    split_f32<<<(int)(nWres / 2048), 256, 0, stream>>>(W_res, Whi, Wlo, (int)nWres);
    split_f32<<<(int)(nWin  / 2048), 256, 0, stream>>>(W_in, Wihi, Wilo, (int)nWin);
    split_f32<<<(int)(nX    / 2048), 256, 0, stream>>>(X, Xhi, Xlo, (int)nX);

    for (int t = 0; t < T_TOT; ++t) {
        const f16 *ph, *pl;
        f16 *nh, *nl;
        if (t & 1) { ph = sBh; pl = sBl; nh = sAh; nl = sAl; }
        else       { ph = sAh; pl = sAl; nh = sBh; nl = sBl; }
        esn_step_fused<<<B_TOT * 4 * 32, 256, 0, stream>>>(
            Xhi, Xlo, Whi, Wlo, Wihi, Wilo, ph, pl, nh, nl,
            W_lin, part, t, t == 0 ? 1 : 0);
    }
    head_reduce<<<T_TOT, 256, 0, stream>>>(part, b_lin, logits, preds);
}

// Round 4
// 1743.892 us; speedup vs baseline: 1.2478x; 1.2424x over previous
//
#include <hip/hip_runtime.h>
#include <stdint.h>

// Echo-state network (fp32 in, fp32 out). Round 18: verbatim R14 step body
// (proven 1791 us; R15-R17 restructures all regressed or crashed) plus ONE
// orthogonal change: a bijective XCD-aware block swizzle.
// Default mapping (XCD = blockIdx % 8; id = b*128+mt*32+it => XCD = it % 8)
// gives each XCD's 96 resident blocks ALL 24 (b,mt) A-slices + 24 B-slices
// ~= 9.2 MB footprint vs 4 MB L2 -> per-step thrash, >=74 MB/step L3 refetch.
// New mapping: XCD x gets the 96 logically-contiguous blocks in (b,it,mt)-
// major order: l = (p&7)*96 + (p>>3). XCD0 then holds b=0, it=0..23, all mt:
// footprint = 4 A-slices (1 MB) + 24 B-slices (3 MB) ~= 4 MB = L2-resident;
// every slice fetched once per step per XCD. Pure index remap - bit-identical
// numerics to R14. Everything else (LDS LDA=72, 2 barriers/chunk, register
// prefetch, hi/lo*4096 split, 3 MFMAs/product, fused head partials,
// head_reduce) is byte-for-byte R14.

typedef _Float16 f16;
typedef _Float16 f16x8 __attribute__((ext_vector_type(8)));
typedef float floatx4 __attribute__((ext_vector_type(4)));

#define N_TOT 256
#define T_TOT 70
#define V_TOT 64
#define B_TOT 6
#define H_TOT 1024
#define C_TOT 4
#define F_TOT (B_TOT * H_TOT)
#define G_TOT 192       // partial groups = B_TOT * 32 unit-tiles
#define LDA 72          // f16 LDS row stride (144 B): <=2-way bank aliasing (free)
#define LO_SCALE 4096.0f
#define LO_INV   (1.0f / 4096.0f)

union H8 { f16 h[8]; uint4 v; };

// ---------------------------------------------------------------------------
// One-time fp32 -> (hi, lo*4096) f16 split, 8 elems/thread. n % 2048 == 0.
// ---------------------------------------------------------------------------
__global__ __launch_bounds__(256)
void split_f32(const float* __restrict__ src, f16* __restrict__ hi,
               f16* __restrict__ lo, int n)
{
    const int i = (blockIdx.x * 256 + threadIdx.x) * 8;
    if (i + 8 > n) return;
    const float4 a = *(const float4*)&src[i];
    const float4 b = *(const float4*)&src[i + 4];
    const float x[8] = {a.x, a.y, a.z, a.w, b.x, b.y, b.z, b.w};
    H8 H, L;
#pragma unroll
    for (int j = 0; j < 8; ++j) {
        const f16 h = (f16)x[j];
        H.h[j] = h;
        L.h[j] = (f16)((x[j] - (float)h) * LO_SCALE);
    }
    *(uint4*)&hi[i] = H.v;
    *(uint4*)&lo[i] = L.v;
}

// ---------------------------------------------------------------------------
// Final head reduce + argmax. Block = t (70), thread = n (256).
// logits[t][n][c] = b_lin[t][c] + sum_g part[t][g][n][c]; preds = argmax.
// Loads are coalesced: consecutive n -> consecutive float4 for fixed g.
// ---------------------------------------------------------------------------
__global__ __launch_bounds__(256)
void head_reduce(const float* __restrict__ part,
                 const float* __restrict__ b_lin,
                 float* __restrict__ logits,
                 float* __restrict__ preds)
{
    const int t = blockIdx.x;
    const int n = threadIdx.x;

    float a0 = b_lin[t * C_TOT + 0];
    float a1 = b_lin[t * C_TOT + 1];
    float a2 = b_lin[t * C_TOT + 2];
    float a3 = b_lin[t * C_TOT + 3];

    const float* p = part + (((size_t)t * G_TOT) * N_TOT + n) * C_TOT;
    for (int g = 0; g < G_TOT; ++g) {
        const float4 v = *(const float4*)&p[(size_t)g * N_TOT * C_TOT];
        a0 += v.x; a1 += v.y; a2 += v.z; a3 += v.w;
    }

    float4 o = {a0, a1, a2, a3};
    *(float4*)&logits[((size_t)t * N_TOT + n) * C_TOT] = o;

    int arg = 0;
    float best = a0;
    if (a1 > best) { best = a1; arg = 1; }
    if (a2 > best) { best = a2; arg = 2; }
    if (a3 > best) { best = a3; arg = 3; }
    preds[(size_t)t * N_TOT + n] = (float)arg;
}

// ---------------------------------------------------------------------------
// Fused step+head: S_new = tanh(S W_res^T + X_t W_in^T); partials -> part[].
// Tile 64(M=batch) x 32(I=units); grid = 6*4*32 = 768. Wave w = M-quadrant,
// 1x2 16x16x32 f16 fragments. BK=64, register-prefetch one chunk ahead.
// Block index XCD-swizzled: l = (p&7)*96 + p>>3, decoded (b,it,mt)-major.
// ---------------------------------------------------------------------------
__global__ __launch_bounds__(256)
void esn_step_fused(const f16* __restrict__ Xhi,   const f16* __restrict__ Xlo,
                    const f16* __restrict__ Whi,   const f16* __restrict__ Wlo,
                    const f16* __restrict__ Wihi,  const f16* __restrict__ Wilo,
                    const f16* __restrict__ shi_p, const f16* __restrict__ slo_p,
                    f16* __restrict__ shi_n,       f16* __restrict__ slo_n,
                    const float* __restrict__ W_lin, float* __restrict__ part,
                    int t, int first)
{
    __shared__ f16 As_hi[64 * LDA];
    __shared__ f16 As_lo[64 * LDA];
    __shared__ f16 Bs_hi[32 * LDA];
    __shared__ f16 Bs_lo[32 * LDA];

    // XCD-aware bijective swizzle (768 % 8 == 0): XCD p&7 gets logical ids
    // [ (p&7)*96, +96 ) in (b,it,mt)-major order -> per-XCD footprint
    // = 4 A-slices + 24 B-slices ~= 4 MB = L2-resident.
    const int p   = blockIdx.x;
    const int l   = (p & 7) * 96 + (p >> 3);
    const int mt  = l & 3;           // batch tile 0..3  (64 rows)
    const int bi  = l >> 2;          // 0..191
    const int b   = bi >> 5;         // reservoir block 0..5
    const int it  = bi & 31;         // unit tile 0..31  (32 cols)

    const int tid  = threadIdx.x;
    const int wm   = tid >> 6;       // wave = M-quadrant
    const int lane = tid & 63;
    const int l16  = lane & 15;
    const int oct  = lane >> 4;

    // staging maps (f16 elements, uint4 = 8 f16)
    const int ra = tid >> 2;          // A row 0..63
    const int ca = (tid & 3) << 4;    // A col {0,16,32,48}: 2 uint4 per buffer
    const int rb = tid >> 3;          // B row 0..31
    const int cb = (tid & 7) << 3;    // B col {0,8,...,56}: 1 uint4 per buffer

    floatx4 acc[2], accl[2];
#pragma unroll
    for (int j = 0; j < 2; ++j) { acc[j] = (floatx4)(0.0f); accl[j] = (floatx4)(0.0f); }

    if (!first) {
        const f16* Ah = shi_p + (size_t)(b * N_TOT + mt * 64 + ra) * H_TOT + ca;
        const f16* Al = slo_p + (size_t)(b * N_TOT + mt * 64 + ra) * H_TOT + ca;
        const f16* Bh = Whi   + (size_t)(b * H_TOT + it * 32 + rb) * H_TOT + cb;
        const f16* Bl = Wlo   + (size_t)(b * H_TOT + it * 32 + rb) * H_TOT + cb;

        uint4 pah0, pah1, pal0, pal1, pbh, pbl;
#define LOAD_CHUNK(J0)                                   \
        do {                                             \
            pah0 = *(const uint4*)&Ah[(J0) + 0];         \
            pah1 = *(const uint4*)&Ah[(J0) + 8];         \
            pal0 = *(const uint4*)&Al[(J0) + 0];         \
            pal1 = *(const uint4*)&Al[(J0) + 8];         \
            pbh  = *(const uint4*)&Bh[(J0)];             \
            pbl  = *(const uint4*)&Bl[(J0)];             \
        } while (0)

        LOAD_CHUNK(0);
        for (int kc = 0; kc < 16; ++kc) {
            if (kc) __syncthreads();   // all waves done reading previous chunk
            *(uint4*)&As_hi[ra * LDA + ca]     = pah0;
            *(uint4*)&As_hi[ra * LDA + ca + 8] = pah1;
            *(uint4*)&As_lo[ra * LDA + ca]     = pal0;
            *(uint4*)&As_lo[ra * LDA + ca + 8] = pal1;
            *(uint4*)&Bs_hi[rb * LDA + cb]     = pbh;
            *(uint4*)&Bs_lo[rb * LDA + cb]     = pbl;
            __syncthreads();
            if (kc < 15) LOAD_CHUNK((kc + 1) * 64);  // overlap w/ ds_read+MFMA

#pragma unroll
            for (int kk = 0; kk < 64; kk += 32) {
                const int ar = (wm * 16 + l16) * LDA + kk + oct * 8;
                const f16x8 ah = *(const f16x8*)&As_hi[ar];
                const f16x8 al = *(const f16x8*)&As_lo[ar];
#pragma unroll
                for (int nf = 0; nf < 2; ++nf) {
                    const int br = (nf * 16 + l16) * LDA + kk + oct * 8;
                    const f16x8 bh = *(const f16x8*)&Bs_hi[br];
                    const f16x8 bl = *(const f16x8*)&Bs_lo[br];
                    acc[nf]  = __builtin_amdgcn_mfma_f32_16x16x32_f16(ah, bh, acc[nf], 0, 0, 0);
                    accl[nf] = __builtin_amdgcn_mfma_f32_16x16x32_f16(ah, bl, accl[nf], 0, 0, 0);
                    accl[nf] = __builtin_amdgcn_mfma_f32_16x16x32_f16(al, bh, accl[nf], 0, 0, 0);
                }
            }
        }
#undef LOAD_CHUNK
        __syncthreads();   // chunk-15 reads done before input-term staging
    }

    // ---- input term: += X_t * W_in[b]^T  (K = V = 64) ----
    {
        const size_t xb = ((size_t)(mt * 64 + ra) * T_TOT + t) * V_TOT + ca;
        *(uint4*)&As_hi[ra * LDA + ca]     = *(const uint4*)&Xhi[xb];
        *(uint4*)&As_hi[ra * LDA + ca + 8] = *(const uint4*)&Xhi[xb + 8];
        *(uint4*)&As_lo[ra * LDA + ca]     = *(const uint4*)&Xlo[xb];
        *(uint4*)&As_lo[ra * LDA + ca + 8] = *(const uint4*)&Xlo[xb + 8];
        const size_t wb = (size_t)(b * H_TOT + it * 32 + rb) * V_TOT + cb;
        *(uint4*)&Bs_hi[rb * LDA + cb] = *(const uint4*)&Wihi[wb];
        *(uint4*)&Bs_lo[rb * LDA + cb] = *(const uint4*)&Wilo[wb];
        __syncthreads();
#pragma unroll
        for (int kk = 0; kk < 64; kk += 32) {
            const int ar = (wm * 16 + l16) * LDA + kk + oct * 8;
            const f16x8 ah = *(const f16x8*)&As_hi[ar];
            const f16x8 al = *(const f16x8*)&As_lo[ar];
#pragma unroll
            for (int nf = 0; nf < 2; ++nf) {
                const int br = (nf * 16 + l16) * LDA + kk + oct * 8;
                const f16x8 bh = *(const f16x8*)&Bs_hi[br];
                const f16x8 bl = *(const f16x8*)&Bs_lo[br];
                acc[nf]  = __builtin_amdgcn_mfma_f32_16x16x32_f16(ah, bh, acc[nf], 0, 0, 0);
                accl[nf] = __builtin_amdgcn_mfma_f32_16x16x32_f16(ah, bl, accl[nf], 0, 0, 0);
                accl[nf] = __builtin_amdgcn_mfma_f32_16x16x32_f16(al, bh, accl[nf], 0, 0, 0);
            }
        }
    }

    // ---- epilogue: tanh -> split-store state; head partial -> part[] ----
    // C/D map (16x16x32): col = lane&15, row = oct*4 + r.
    const int nbase = mt * 64;
    const int ibase = it * 32;

    const float* wl = W_lin + (size_t)t * C_TOT * F_TOT + b * H_TOT + ibase;
    float w[4][2];
#pragma unroll
    for (int c = 0; c < 4; ++c)
#pragma unroll
        for (int nf = 0; nf < 2; ++nf)
            w[c][nf] = wl[(size_t)c * F_TOT + nf * 16 + l16];

    float sval[2][4];
#pragma unroll
    for (int nf = 0; nf < 2; ++nf)
#pragma unroll
        for (int r = 0; r < 4; ++r) {
            const int m  = wm * 16 + oct * 4 + r;   // batch row within tile
            const int ii = nf * 16 + l16;           // unit col within tile
            const float s = tanhf(acc[nf][r] + accl[nf][r] * LO_INV);
            sval[nf][r] = s;
            const f16 h = (f16)s;
            const size_t oidx = (size_t)(b * N_TOT + nbase + m) * H_TOT + ibase + ii;
            shi_n[oidx] = h;
            slo_n[oidx] = (f16)((s - (float)h) * LO_SCALE);
        }

    const int g = b * 32 + it;
#pragma unroll
    for (int r = 0; r < 4; ++r) {
        float v[4];
#pragma unroll
        for (int c = 0; c < 4; ++c) {
            float x = sval[0][r] * w[c][0] + sval[1][r] * w[c][1];
            x += __shfl_xor(x, 1);
            x += __shfl_xor(x, 2);
            x += __shfl_xor(x, 4);
            x += __shfl_xor(x, 8);
            v[c] = x;
        }
        if (l16 == 0) {
            const int n = nbase + wm * 16 + oct * 4 + r;
            float4 o = {v[0], v[1], v[2], v[3]};
            *(float4*)&part[(((size_t)t * G_TOT + g) * N_TOT + n) * C_TOT] = o;
        }
    }
}

extern "C" void kernel_launch(void* const* d_in, const int* in_sizes, int n_in,
                              void* d_out, int out_size, void* d_ws, size_t ws_size,
                              hipStream_t stream) {
    const float* X     = (const float*)d_in[0]; // [256,70,64]
    const float* W_res = (const float*)d_in[1]; // [6,1024,1024]
    const float* W_in  = (const float*)d_in[2]; // [6,1024,64]
    const float* W_lin = (const float*)d_in[3]; // [70,4,6144]
    const float* b_lin = (const float*)d_in[4]; // [70,4]

    float* out    = (float*)d_out;
    float* logits = out;                                  // T*N*C fp32
    float* preds  = out + (size_t)T_TOT * N_TOT * C_TOT;  // T*N   fp32

    const size_t nWres = (size_t)B_TOT * H_TOT * H_TOT;   // 6,291,456
    const size_t nWin  = (size_t)B_TOT * H_TOT * V_TOT;   //   393,216
    const size_t nX    = (size_t)N_TOT * T_TOT * V_TOT;   // 1,146,880
    const size_t nS    = (size_t)B_TOT * N_TOT * H_TOT;   // 1,572,864

    f16* p    = (f16*)d_ws;                               // f16 arena ~43.9 MB
    f16* Whi  = p;  p += nWres;
    f16* Wlo  = p;  p += nWres;
    f16* Wihi = p;  p += nWin;
    f16* Wilo = p;  p += nWin;
    f16* Xhi  = p;  p += nX;
    f16* Xlo  = p;  p += nX;
    f16* sAh  = p;  p += nS;
    f16* sAl  = p;  p += nS;
    f16* sBh  = p;  p += nS;
    f16* sBl  = p;  p += nS;
    float* part = (float*)p;                              // +55 MB (ws ~268 MB)

    // one-time pre-splits (stream-ordered before the loop)
    split_f32<<<(int)(nWres / 2048), 256, 0, stream>>>(W_res, Whi, Wlo, (int)nWres);
    split_f32<<<(int)(nWin  / 2048), 256, 0, stream>>>(W_in, Wihi, Wilo, (int)nWin);
    split_f32<<<(int)(nX    / 2048), 256, 0, stream>>>(X, Xhi, Xlo, (int)nX);

    for (int t = 0; t < T_TOT; ++t) {
        const f16 *ph, *pl;
        f16 *nh, *nl;
        if (t & 1) { ph = sBh; pl = sBl; nh = sAh; nl = sAl; }
        else       { ph = sAh; pl = sAl; nh = sBh; nl = sBl; }
        esn_step_fused<<<B_TOT * 4 * 32, 256, 0, stream>>>(
            Xhi, Xlo, Whi, Wlo, Wihi, Wilo, ph, pl, nh, nl,
            W_lin, part, t, t == 0 ? 1 : 0);
    }
    head_reduce<<<T_TOT, 256, 0, stream>>>(part, b_lin, logits, preds);
}